// Round 4
// baseline (83.516 us; speedup 1.0000x reference)
//
#include <hip/hip_runtime.h>
#include <math.h>
#include <float.h>

#define B_ 64
#define T_ 100
#define N_ 20000
#define NQ (B_ * T_)              // 6400 queries
#define NCHUNKS 100
#define CHUNK (N_ / NCHUNKS)      // 200 points per chunk
#define PAIRS_TOTAL (N_ / 2)      // 10000
#define CPAIRS (CHUNK / 2)        // 100 pairs per chunk
#define GROUPS (CPAIRS / 2)       // 50 groups (4 points) per chunk
#define QG 256                    // queries per block
#define NQG (NQ / QG)             // 25
#define K1_THREADS 128            // 2 queries per thread

typedef float f2 __attribute__((ext_vector_type(2)));
typedef float f4 __attribute__((ext_vector_type(4)));
typedef unsigned long long u64;

// ws layout:
//   pts  f4[2 * PAIRS_TOTAL]  (320 KB)  pair-interleaved (-2g, |g|^2) table
//   keys u64[NQ]              (51.2 KB) packed (sortable(e)<<32)|idx, atomicMin
#define PTS_OFF  0
#define KEYS_OFF (2 * PAIRS_TOTAL * sizeof(f4))

// Map f32 -> u32 preserving < order for all finite values (incl. negatives).
__device__ __forceinline__ unsigned int f32_sortable(float f) {
    unsigned int u = __float_as_uint(f);
    return ((int)u >= 0) ? (u | 0x80000000u) : ~u;
}

// ---------------------------------------------------------------------------
// Kernel 0: build the global-frame point table (batch-independent), init keys
// and the output accumulator. Pair p -> pts[2p]   = {-2x0,-2x1,-2y0,-2y1}
//                                      pts[2p+1] = {-2z0,-2z1, p2_0, p2_1}
// A group of 4 points = 4 consecutive f4 = 64 B -> one s_load_dwordx16 in k1.
// ---------------------------------------------------------------------------
__global__ __launch_bounds__(256) void k0_prep(
    const float* __restrict__ boundary,   // [4,N]
    f4* __restrict__ pts,
    u64* __restrict__ keys,
    float* __restrict__ out)
{
    const int i = blockIdx.x * 256 + threadIdx.x;   // grid covers 10240
    if (i < PAIRS_TOTAL) {
        const int n0 = 2 * i;
        const float x0 = boundary[n0],          x1 = boundary[n0 + 1];
        const float y0 = boundary[N_ + n0],     y1 = boundary[N_ + n0 + 1];
        const float z0 = boundary[2 * N_ + n0], z1 = boundary[2 * N_ + n0 + 1];
        f4 a = { -2.f * x0, -2.f * x1, -2.f * y0, -2.f * y1 };
        f4 b = { -2.f * z0, -2.f * z1,
                 x0 * x0 + y0 * y0 + z0 * z0,
                 x1 * x1 + y1 * y1 + z1 * z1 };
        pts[2 * i]     = a;
        pts[2 * i + 1] = b;
    }
    if (i < NQ) keys[i] = ~0ull;
    if (i == 0) out[0] = 0.0f;
}

// ---------------------------------------------------------------------------
// Kernel 1: global-frame partial 1-NN. Block = (query-group, chunk).
// Rigid transforms preserve distance: |w - R^T(g-t)| = |(Rw+t) - g|, so the
// NN search runs in the global frame with batch-independent point data.
// Point data is BLOCK-UNIFORM -> read through the scalar pipe (s_load from
// the L2-hot 320 KB table), NOT LDS: kills the ds_read issue bottleneck.
// Each thread owns 2 queries; one u64 atomicMin per (query, chunk).
// ---------------------------------------------------------------------------
__global__ __launch_bounds__(K1_THREADS) void k1_nn(
    const float* __restrict__ poses,      // [B,4,4]
    const float* __restrict__ wpts,       // [B,T,3]
    const f4* __restrict__ pts,           // [2*PAIRS_TOTAL]
    u64* __restrict__ keys)               // [NQ]
{
    const int bx   = blockIdx.x;
    const int qg   = bx / NCHUNKS;
    const int c    = bx - qg * NCHUNKS;
    const int base = c * CHUNK;
    const int tid  = threadIdx.x;

    // chunk's slice of the table: GROUPS groups of 4 consecutive f4
    const f4* __restrict__ pp = pts + 2 * (c * CPAIRS);

    // ---- per-thread queries: global waypoint q = R w + t ----
    const int i0 = qg * QG + tid;
    const int i1 = i0 + K1_THREADS;

    float q0x, q0y, q0z, q1x, q1y, q1z;
    {
        int b0 = i0 / T_;
        const float* P = poses + b0 * 16;
        const float* W = wpts + i0 * 3;
        float wx = W[0], wy = W[1], wz = W[2];
        q0x = P[0] * wx + P[1] * wy + P[2]  * wz + P[3];
        q0y = P[4] * wx + P[5] * wy + P[6]  * wz + P[7];
        q0z = P[8] * wx + P[9] * wy + P[10] * wz + P[11];
    }
    {
        int b1 = i1 / T_;
        const float* P = poses + b1 * 16;
        const float* W = wpts + i1 * 3;
        float wx = W[0], wy = W[1], wz = W[2];
        q1x = P[0] * wx + P[1] * wy + P[2]  * wz + P[3];
        q1y = P[4] * wx + P[5] * wy + P[6]  * wz + P[7];
        q1z = P[8] * wx + P[9] * wy + P[10] * wz + P[11];
    }

    const f2 v0x = { q0x, q0x }, v0y = { q0y, q0y }, v0z = { q0z, q0z };
    const f2 v1x = { q1x, q1x }, v1y = { q1y, q1y }, v1z = { q1z, q1z };

    float best0 = FLT_MAX, best1 = FLT_MAX;
    int   bg0 = 0, bg1 = 0;

#pragma unroll 4
    for (int g = 0; g < GROUPS; ++g) {
        // uniform index -> scalar loads (s_load_dwordx16 per group)
        const f4 a0 = pp[4 * g + 0], b0 = pp[4 * g + 1];
        const f4 a1 = pp[4 * g + 2], b1 = pp[4 * g + 3];
        const f2 mx0 = { a0.x, a0.y }, my0 = { a0.z, a0.w };
        const f2 mz0 = { b0.x, b0.y }, p20 = { b0.z, b0.w };
        const f2 mx1 = { a1.x, a1.y }, my1 = { a1.z, a1.w };
        const f2 mz1 = { b1.x, b1.y }, p21 = { b1.z, b1.w };

        // e = p2 - 2 q.g  (3 packed FMAs per 2 points)
        f2 eA = __builtin_elementwise_fma(mx0, v0x,
                __builtin_elementwise_fma(my0, v0y,
                __builtin_elementwise_fma(mz0, v0z, p20)));
        f2 eB = __builtin_elementwise_fma(mx1, v0x,
                __builtin_elementwise_fma(my1, v0y,
                __builtin_elementwise_fma(mz1, v0z, p21)));
        float m0 = fminf(fminf(eA.x, eA.y), fminf(eB.x, eB.y));
        if (m0 < best0) { best0 = m0; bg0 = g; }

        f2 eC = __builtin_elementwise_fma(mx0, v1x,
                __builtin_elementwise_fma(my0, v1y,
                __builtin_elementwise_fma(mz0, v1z, p20)));
        f2 eD = __builtin_elementwise_fma(mx1, v1x,
                __builtin_elementwise_fma(my1, v1y,
                __builtin_elementwise_fma(mz1, v1z, p21)));
        float m1 = fminf(fminf(eC.x, eC.y), fminf(eD.x, eD.y));
        if (m1 < best1) { best1 = m1; bg1 = g; }
    }

    // ---- resolve exact index inside winning group ----
    // Divergent index -> vector loads, but only once per thread. Same IEEE
    // fma sequence as the main loop -> bitwise-identical e values.
    {
        const f4 a0 = pp[4 * bg0 + 0], b0 = pp[4 * bg0 + 1];
        const f4 a1 = pp[4 * bg0 + 2], b1 = pp[4 * bg0 + 3];
        const f2 mx0 = { a0.x, a0.y }, my0 = { a0.z, a0.w };
        const f2 mz0 = { b0.x, b0.y }, p20 = { b0.z, b0.w };
        const f2 mx1 = { a1.x, a1.y }, my1 = { a1.z, a1.w };
        const f2 mz1 = { b1.x, b1.y }, p21 = { b1.z, b1.w };
        f2 eA = __builtin_elementwise_fma(mx0, v0x,
                __builtin_elementwise_fma(my0, v0y,
                __builtin_elementwise_fma(mz0, v0z, p20)));
        f2 eB = __builtin_elementwise_fma(mx1, v0x,
                __builtin_elementwise_fma(my1, v0y,
                __builtin_elementwise_fma(mz1, v0z, p21)));
        int loc = 4 * bg0;
        int li = (eA.x == best0) ? loc
               : (eA.y == best0) ? loc + 1
               : (eB.x == best0) ? loc + 2 : loc + 3;
        u64 key = ((u64)f32_sortable(best0) << 32) | (unsigned)(base + li);
        atomicMin(&keys[i0], key);
    }
    {
        const f4 a0 = pp[4 * bg1 + 0], b0 = pp[4 * bg1 + 1];
        const f4 a1 = pp[4 * bg1 + 2], b1 = pp[4 * bg1 + 3];
        const f2 mx0 = { a0.x, a0.y }, my0 = { a0.z, a0.w };
        const f2 mz0 = { b0.x, b0.y }, p20 = { b0.z, b0.w };
        const f2 mx1 = { a1.x, a1.y }, my1 = { a1.z, a1.w };
        const f2 mz1 = { b1.x, b1.y }, p21 = { b1.z, b1.w };
        f2 eC = __builtin_elementwise_fma(mx0, v1x,
                __builtin_elementwise_fma(my0, v1y,
                __builtin_elementwise_fma(mz0, v1z, p20)));
        f2 eD = __builtin_elementwise_fma(mx1, v1x,
                __builtin_elementwise_fma(my1, v1y,
                __builtin_elementwise_fma(mz1, v1z, p21)));
        int loc = 4 * bg1;
        int li = (eC.x == best1) ? loc
               : (eC.y == best1) ? loc + 1
               : (eD.x == best1) ? loc + 2 : loc + 3;
        u64 key = ((u64)f32_sortable(best1) << 32) | (unsigned)(base + li);
        atomicMin(&keys[i1], key);
    }
}

// ---------------------------------------------------------------------------
// Kernel 2: per query, unpack winning index, global-frame epilogue:
// dots = (q - g) . n  (rotation-invariant == reference's local-frame dot),
// ExpRelu, block-reduce, atomicAdd into out (zeroed by k0).
// ---------------------------------------------------------------------------
__global__ __launch_bounds__(256) void k2_epilogue(
    const float* __restrict__ poses,
    const float* __restrict__ wpts,
    const float* __restrict__ boundary,   // [4,N]
    const float* __restrict__ bnorm,      // [3,N]
    const u64* __restrict__ keys,
    float* __restrict__ out)
{
    const int tid = threadIdx.x;
    const int i = blockIdx.x * 256 + tid;     // grid = 25 -> i in [0,6400)

    const int bi = (int)(unsigned)(keys[i] & 0xFFFFFFFFull);

    const int b = i / T_;
    const float* P = poses + b * 16;
    const float* W = wpts + i * 3;
    const float wx = W[0], wy = W[1], wz = W[2];
    const float qx = P[0] * wx + P[1] * wy + P[2]  * wz + P[3];
    const float qy = P[4] * wx + P[5] * wy + P[6]  * wz + P[7];
    const float qz = P[8] * wx + P[9] * wy + P[10] * wz + P[11];

    const float gx = boundary[bi], gy = boundary[N_ + bi], gz = boundary[2 * N_ + bi];
    const float nx = bnorm[bi],    ny = bnorm[N_ + bi],    nz = bnorm[2 * N_ + bi];

    const float dots = (qx - gx) * nx + (qy - gy) * ny + (qz - gz) * nz;
    // ExpRelu: alpha=1, beta=0.5; pre-scaled for the final mean
    float val = (dots > 0.0f) ? (dots + 1.0f) : expf(0.5f * dots);
    val *= (1.0f / (float)NQ);

    __shared__ float red[256];
    red[tid] = val;
    __syncthreads();
#pragma unroll
    for (int s = 128; s > 0; s >>= 1) {
        if (tid < s) red[tid] += red[tid + s];
        __syncthreads();
    }
    if (tid == 0) atomicAdd(out, red[0]);
}

extern "C" void kernel_launch(void* const* d_in, const int* in_sizes, int n_in,
                              void* d_out, int out_size, void* d_ws, size_t ws_size,
                              hipStream_t stream) {
    const float* poses    = (const float*)d_in[0];
    const float* wpts     = (const float*)d_in[1];
    const float* boundary = (const float*)d_in[2];
    const float* bnorm    = (const float*)d_in[3];
    float* out = (float*)d_out;

    f4*  pts  = (f4*)((char*)d_ws + PTS_OFF);
    u64* keys = (u64*)((char*)d_ws + KEYS_OFF);

    k0_prep<<<(PAIRS_TOTAL + 255) / 256, 256, 0, stream>>>(
        boundary, pts, keys, out);
    k1_nn<<<NQG * NCHUNKS, K1_THREADS, 0, stream>>>(
        poses, wpts, pts, keys);
    k2_epilogue<<<NQ / 256, 256, 0, stream>>>(
        poses, wpts, boundary, bnorm, keys, out);
}